// Round 1
// baseline (19.195 us; speedup 1.0000x reference)
//
#include <hip/hip_runtime.h>

// InfoNCE-on-image-norms:
//   norms = ||img_i||_2 over CHW (150528 elems each), 64 pos + 64 neg
//   mu, std (ddof=0) over all 128 norms; denom = std*0.7
//   loss = -log(sum_pos exp((n-mu)/denom) / (sum_pos + sum_neg))
//
// Stage 1: 128 images x 7 chunks = 896 blocks, 256 thr.
//   Per thread: 21 float4 loads (coalesced, 16B/lane), sum of squares.
//   Wave shuffle reduce -> LDS across 4 waves -> one float partial per block.
// Stage 2: 1 block x 128 thr. Thread t owns image t. Double-precision stats.

#define IMG_ELEMS   150528          // 3*224*224
#define VEC_PER_IMG 37632           // IMG_ELEMS/4
#define CHUNKS      7
#define VEC_PER_CHK 5376            // 37632/7
#define ITERS       21              // 5376/256
#define TEMPERATURE 0.7

__global__ __launch_bounds__(256) void sumsq_kernel(const float* __restrict__ pos,
                                                    const float* __restrict__ neg,
                                                    float* __restrict__ partials) {
    const int bid   = blockIdx.x;          // 0..895
    const int img   = bid / CHUNKS;        // 0..127
    const int chunk = bid % CHUNKS;        // 0..6

    const float* base = (img < 64) ? (pos + (size_t)img * IMG_ELEMS)
                                   : (neg + (size_t)(img - 64) * IMG_ELEMS);
    const float4* src = (const float4*)base;

    int idx = chunk * VEC_PER_CHK + threadIdx.x;
    float acc = 0.0f;
#pragma unroll
    for (int i = 0; i < ITERS; ++i) {
        float4 v = src[idx + i * 256];
        acc += v.x * v.x + v.y * v.y + v.z * v.z + v.w * v.w;
    }

    // 64-lane wave reduction
#pragma unroll
    for (int off = 32; off > 0; off >>= 1)
        acc += __shfl_down(acc, off, 64);

    __shared__ float lds[4];
    const int wave = threadIdx.x >> 6;
    const int lane = threadIdx.x & 63;
    if (lane == 0) lds[wave] = acc;
    __syncthreads();
    if (threadIdx.x == 0)
        partials[bid] = lds[0] + lds[1] + lds[2] + lds[3];
}

__global__ __launch_bounds__(128) void loss_kernel(const float* __restrict__ partials,
                                                   float* __restrict__ out) {
    const int t = threadIdx.x;             // 0..127 ; wave0 = pos, wave1 = neg
    const int wave = t >> 6;
    const int lane = t & 63;

    float s = 0.0f;
#pragma unroll
    for (int i = 0; i < CHUNKS; ++i) s += partials[t * CHUNKS + i];
    const double norm = sqrt((double)s);

    // mean / E[x^2] over all 128 norms (double)
    double sum = norm, sumsq = norm * norm;
#pragma unroll
    for (int off = 32; off > 0; off >>= 1) {
        sum   += __shfl_down(sum,   off, 64);
        sumsq += __shfl_down(sumsq, off, 64);
    }
    __shared__ double red[4];
    if (lane == 0) { red[wave * 2] = sum; red[wave * 2 + 1] = sumsq; }
    __syncthreads();

    const double tot   = red[0] + red[2];
    const double totsq = red[1] + red[3];
    const double mu    = tot / 128.0;
    double var         = totsq / 128.0 - mu * mu;
    if (var < 0.0) var = 0.0;
    const double denom = sqrt(var) * TEMPERATURE;

    const double e = exp((norm - mu) / denom);

    // per-wave sum: wave0 -> pos_sim, wave1 -> neg_sim
    double esum = e;
#pragma unroll
    for (int off = 32; off > 0; off >>= 1)
        esum += __shfl_down(esum, off, 64);

    __shared__ double sims[2];
    if (lane == 0) sims[wave] = esum;
    __syncthreads();

    if (t == 0) {
        const double ps = sims[0];
        const double ns = sims[1];
        out[0] = (float)(-log(ps / (ps + ns)));
    }
}

extern "C" void kernel_launch(void* const* d_in, const int* in_sizes, int n_in,
                              void* d_out, int out_size, void* d_ws, size_t ws_size,
                              hipStream_t stream) {
    const float* pos = (const float*)d_in[0];
    const float* neg = (const float*)d_in[1];
    float* partials  = (float*)d_ws;        // 896 floats
    float* out       = (float*)d_out;       // 1 float

    sumsq_kernel<<<128 * CHUNKS, 256, 0, stream>>>(pos, neg, partials);
    loss_kernel<<<1, 128, 0, stream>>>(partials, out);
}